// Round 12
// baseline (257.874 us; speedup 1.0000x reference)
//
#include <hip/hip_runtime.h>
#include <hip/hip_bf16.h>
#include <math.h>

#define WAVE 64

// R9 structure with ONE change: the 1.074 GB zero-fill moves from
// hipMemsetAsync into the softmax kernel (disjoint buffers -> no sync
// needed; the ~10 us of softmax work rides inside the BW-bound fill).
// Fill shape is a clean replica of rocclr fillBufferAligned: 2048 blocks
// x 256 threads, flat grid-stride float4 stores, no selects, no dual
// streams, no cooperative machinery (prior hand-fill failures were each
// confounded by exactly one of those).
// chunk_hist and rank_scatter byte-identical to R9 (195 us champion).

// ---------------- K1: zero-fill + softmax + top1/top2 ----------------
// Wave w of block b handles token s = b*4 + w (one wave per token, R9's
// parallelism). Then all 2048 blocks stream float4 zeros over the output.
__global__ void __launch_bounds__(256)
fill_softmax_top2(const float* __restrict__ x,
                  float* __restrict__ out,
                  int* __restrict__ top1,
                  int* __restrict__ top2,
                  float* __restrict__ w1,
                  float* __restrict__ w2,
                  int S, size_t n4) {
    const int wid  = threadIdx.x >> 6;
    const int lane = threadIdx.x & 63;
    const int s = blockIdx.x * 4 + wid;

    // ---- softmax + top2 (identical math to R9) ----
    if (s < S) {
        float v = x[(size_t)s * 64 + lane];

        // argmax with lowest-index tiebreak (matches jnp.argmax)
        float bv = v; int bi = lane;
        #pragma unroll
        for (int off = 32; off >= 1; off >>= 1) {
            float ov = __shfl_xor(bv, off, WAVE);
            int   oi = __shfl_xor(bi, off, WAVE);
            if (ov > bv || (ov == bv && oi < bi)) { bv = ov; bi = oi; }
        }
        const float m = bv;
        const int t1 = bi;

        float e = expf(v - m);
        float sum = e;
        #pragma unroll
        for (int off = 32; off >= 1; off >>= 1) sum += __shfl_xor(sum, off, WAVE);
        const float p = e / sum;

        float v2 = (lane == t1) ? -INFINITY : v;
        float bv2 = v2; int bi2 = lane;
        #pragma unroll
        for (int off = 32; off >= 1; off >>= 1) {
            float ov = __shfl_xor(bv2, off, WAVE);
            int   oi = __shfl_xor(bi2, off, WAVE);
            if (ov > bv2 || (ov == bv2 && oi < bi2)) { bv2 = ov; bi2 = oi; }
        }
        const int t2 = bi2;

        const float p1 = __shfl(p, t1, WAVE);
        const float p2 = __shfl(p, t2, WAVE);

        if (lane == 0) {
            top1[s] = t1; top2[s] = t2;
            w1[s] = p1;   w2[s] = p2;
        }
    }

    // ---- clean flat grid-stride zero-fill (both output tensors) ----
    {
        float4* out4 = (float4*)out;
        const size_t stride = (size_t)gridDim.x * blockDim.x;
        const float4 z = make_float4(0.0f, 0.0f, 0.0f, 0.0f);
        #pragma unroll 4
        for (size_t i = (size_t)blockIdx.x * blockDim.x + threadIdx.x;
             i < n4; i += stride)
            out4[i] = z;
    }
}

// ---------------- K2: per-chunk expert histograms (identical to R9) -------
__global__ void chunk_hist(const int* __restrict__ top1,
                           const int* __restrict__ top2,
                           int* __restrict__ hist1,
                           int* __restrict__ hist2) {
    const int c = blockIdx.x;
    const int lane = threadIdx.x;
    const int t1 = top1[c * 64 + lane];
    const int t2 = top2[c * 64 + lane];
    int c1 = 0, c2 = 0;
    #pragma unroll 8
    for (int j = 0; j < 64; ++j) {
        c1 += (__shfl(t1, j, WAVE) == lane);
        c2 += (__shfl(t2, j, WAVE) == lane);
    }
    hist1[c * 64 + lane] = c1;
    hist2[c * 64 + lane] = c2;
}

// ---------------- K3: fused scan + ranks + scatter (identical to R9) ------
__global__ void rank_scatter(const int* __restrict__ top1,
                             const int* __restrict__ top2,
                             const float* __restrict__ w1,
                             const float* __restrict__ w2,
                             const int* __restrict__ hist1,
                             const int* __restrict__ hist2,
                             float* __restrict__ out,
                             int S, int CAP, int nchunks) {
    const int c = blockIdx.x;
    const int i = threadIdx.x;
    const int s = c * 64 + i;

    int b1 = 0, b2 = 0, tot1 = 0;
    #pragma unroll 8
    for (int cc = 0; cc < nchunks; ++cc) {
        const int h1 = hist1[cc * 64 + i];
        const int h2 = hist2[cc * 64 + i];
        const int lt = (cc < c);
        b1   += lt ? h1 : 0;
        b2   += lt ? h2 : 0;
        tot1 += h1;
    }

    const int t1 = top1[s];
    const int t2 = top2[s];

    int cnt1 = 0, cnt2 = 0;
    #pragma unroll 8
    for (int j = 0; j < 64; ++j) {
        const int o1 = __shfl(t1, j, WAVE);
        const int o2 = __shfl(t2, j, WAVE);
        cnt1 += (o1 == t1) && (j < i);
        cnt2 += (o2 == t2) && (j < i);
    }

    const int rank1 = __shfl(b1, t1, WAVE) + cnt1;
    const int rank2 = __shfl(b2, t2, WAVE) + cnt2 + __shfl(tot1, t2, WAVE);

    const size_t secoff = (size_t)S * 64 * CAP;
    if (rank1 < CAP) {
        const size_t idx = ((size_t)s * 64 + t1) * CAP + rank1;
        out[idx] = w1[s];
        out[secoff + idx] = 1.0f;
    }
    if (rank2 < CAP) {
        const size_t idx = ((size_t)s * 64 + t2) * CAP + rank2;
        out[idx] = w2[s];
        out[secoff + idx] = 1.0f;
    }
}

extern "C" void kernel_launch(void* const* d_in, const int* in_sizes, int n_in,
                              void* d_out, int out_size, void* d_ws, size_t ws_size,
                              hipStream_t stream) {
    const float* x = (const float*)d_in[0];
    float* out = (float*)d_out;

    const int E = 64;
    const int S = in_sizes[0] / E;            // 8192
    int cap = (int)(2.0 * S / E);
    cap += cap % 2;
    if (cap < 4) cap = 4;                     // 256

    const int nchunks = S / 64;               // 128
    const size_t n4 = (size_t)out_size >> 2;  // total float4s (both tensors)

    // workspace layout (all 4-byte elements)
    char* w = (char*)d_ws;
    int*   top1   = (int*)w;   w += (size_t)S * 4;
    int*   top2   = (int*)w;   w += (size_t)S * 4;
    float* w1     = (float*)w; w += (size_t)S * 4;
    float* w2     = (float*)w; w += (size_t)S * 4;
    int*   hist1  = (int*)w;   w += (size_t)nchunks * 64 * 4;
    int*   hist2  = (int*)w;   w += (size_t)nchunks * 64 * 4;

    // 1) fused zero-fill + softmax + top2 (2048 blocks; fill hides softmax)
    {
        const int blocks = S / 4;             // one wave per token
        fill_softmax_top2<<<blocks, 256, 0, stream>>>(x, out, top1, top2,
                                                      w1, w2, S, n4);
    }

    // 2) per-chunk histograms
    chunk_hist<<<nchunks, 64, 0, stream>>>(top1, top2, hist1, hist2);

    // 3) fused scan + ranks + scatter
    rank_scatter<<<nchunks, 64, 0, stream>>>(top1, top2, w1, w2,
                                             hist1, hist2, out,
                                             S, cap, nchunks);
}

// Round 13
// 194.678 us; speedup vs baseline: 1.3246x; 1.3246x over previous
//
#include <hip/hip_runtime.h>
#include <hip/hip_bf16.h>
#include <math.h>

#define WAVE 64

// R9 champion (195 us) micro-opt round: hist1/hist2 packed as int2 (halves
// scan loads in rank_scatter), loads hoisted ahead of the scan loop.
// Structure, shapes, and ordering identical to R9.
// Laws: hipMemsetAsync is the only ~6.5 TB/s filler (R2/R6/R10/R12 all
// ~4-5 TB/s); avoid sparse-grid ballot shapes (+30 us, R4/R5/R8); avoid
// serial scans (R1->R9 -28 us); avoid cooperative (R10 +198 us); keep
// one-wave-per-token softmax parallelism (R11 +20 us).

// ---------------- K1: per-token softmax + top1/top2 ----------------
__global__ void router_softmax_top2(const float* __restrict__ x,
                                    int* __restrict__ top1,
                                    int* __restrict__ top2,
                                    float* __restrict__ w1,
                                    float* __restrict__ w2,
                                    int S) {
    const int wavesPerBlock = blockDim.x >> 6;
    const int wid  = threadIdx.x >> 6;
    const int lane = threadIdx.x & 63;
    const int s = blockIdx.x * wavesPerBlock + wid;
    if (s >= S) return;

    float v = x[(size_t)s * 64 + lane];

    // argmax with lowest-index tiebreak (matches jnp.argmax)
    float bv = v; int bi = lane;
    #pragma unroll
    for (int off = 32; off >= 1; off >>= 1) {
        float ov = __shfl_xor(bv, off, WAVE);
        int   oi = __shfl_xor(bi, off, WAVE);
        if (ov > bv || (ov == bv && oi < bi)) { bv = ov; bi = oi; }
    }
    const float m = bv;
    const int t1 = bi;

    // fp32 softmax
    float e = expf(v - m);
    float sum = e;
    #pragma unroll
    for (int off = 32; off >= 1; off >>= 1) sum += __shfl_xor(sum, off, WAVE);
    const float p = e / sum;

    // second argmax with top1 masked out
    float v2 = (lane == t1) ? -INFINITY : v;
    float bv2 = v2; int bi2 = lane;
    #pragma unroll
    for (int off = 32; off >= 1; off >>= 1) {
        float ov = __shfl_xor(bv2, off, WAVE);
        int   oi = __shfl_xor(bi2, off, WAVE);
        if (ov > bv2 || (ov == bv2 && oi < bi2)) { bv2 = ov; bi2 = oi; }
    }
    const int t2 = bi2;

    const float p1 = __shfl(p, t1, WAVE);
    const float p2 = __shfl(p, t2, WAVE);

    if (lane == 0) {
        top1[s] = t1; top2[s] = t2;
        w1[s] = p1;   w2[s] = p2;
    }
}

// ---------------- K2: per-chunk expert histograms (packed int2) ----------
__global__ void chunk_hist(const int* __restrict__ top1,
                           const int* __restrict__ top2,
                           int2* __restrict__ hist) {
    const int c = blockIdx.x;
    const int lane = threadIdx.x;
    const int t1 = top1[c * 64 + lane];
    const int t2 = top2[c * 64 + lane];
    int c1 = 0, c2 = 0;
    #pragma unroll 8
    for (int j = 0; j < 64; ++j) {
        c1 += (__shfl(t1, j, WAVE) == lane);
        c2 += (__shfl(t2, j, WAVE) == lane);
    }
    hist[c * 64 + lane] = make_int2(c1, c2);
}

// ---------------- K3: fused scan + ranks + scatter ----------------
// One 64-lane block per chunk. Thread i = expert i for the scan phase
// (one dwordx2 load per chunk), then token-i role for the stable count.
__global__ void rank_scatter(const int* __restrict__ top1,
                             const int* __restrict__ top2,
                             const float* __restrict__ w1,
                             const float* __restrict__ w2,
                             const int2* __restrict__ hist,
                             float* __restrict__ out,
                             int S, int CAP, int nchunks) {
    const int c = blockIdx.x;
    const int i = threadIdx.x;
    const int s = c * 64 + i;

    // hoisted token loads (overlap with the scan loop)
    const int t1 = top1[s];
    const int t2 = top2[s];
    const float v1 = w1[s];
    const float v2 = w2[s];

    // scan phase: thread i accumulates expert-i counts (1 dwordx2/iter)
    int b1 = 0, b2 = 0, tot1 = 0;
    #pragma unroll 8
    for (int cc = 0; cc < nchunks; ++cc) {
        const int2 h = hist[cc * 64 + i];
        const int lt = (cc < c);
        b1   += lt ? h.x : 0;
        b2   += lt ? h.y : 0;
        tot1 += h.x;                // full pre-drop top-1 count of expert i
    }

    // within-chunk stable counts
    int cnt1 = 0, cnt2 = 0;
    #pragma unroll 8
    for (int j = 0; j < 64; ++j) {
        const int o1 = __shfl(t1, j, WAVE);
        const int o2 = __shfl(t2, j, WAVE);
        cnt1 += (o1 == t1) && (j < i);
        cnt2 += (o2 == t2) && (j < i);
    }

    const int rank1 = __shfl(b1, t1, WAVE) + cnt1;
    const int rank2 = __shfl(b2, t2, WAVE) + cnt2 + __shfl(tot1, t2, WAVE);

    const size_t secoff = (size_t)S * 64 * CAP;
    if (rank1 < CAP) {
        const size_t idx = ((size_t)s * 64 + t1) * CAP + rank1;
        out[idx] = v1;
        out[secoff + idx] = 1.0f;
    }
    if (rank2 < CAP) {
        const size_t idx = ((size_t)s * 64 + t2) * CAP + rank2;
        out[idx] = v2;
        out[secoff + idx] = 1.0f;
    }
}

extern "C" void kernel_launch(void* const* d_in, const int* in_sizes, int n_in,
                              void* d_out, int out_size, void* d_ws, size_t ws_size,
                              hipStream_t stream) {
    const float* x = (const float*)d_in[0];
    float* out = (float*)d_out;

    const int E = 64;
    const int S = in_sizes[0] / E;            // 8192
    int cap = (int)(2.0 * S / E);
    cap += cap % 2;
    if (cap < 4) cap = 4;                     // 256

    const int nchunks = S / 64;               // 128

    // workspace layout
    char* w = (char*)d_ws;
    int*   top1  = (int*)w;    w += (size_t)S * 4;
    int*   top2  = (int*)w;    w += (size_t)S * 4;
    float* w1    = (float*)w;  w += (size_t)S * 4;
    float* w2    = (float*)w;  w += (size_t)S * 4;
    int2*  hist  = (int2*)w;   w += (size_t)nchunks * 64 * 8;

    // 1) zero the dense output FIRST (the roofline term; ~6.5 TB/s)
    hipMemsetAsync(d_out, 0, (size_t)out_size * sizeof(float), stream);

    // 2) softmax + top2 (one wave per token, 2048 blocks)
    {
        const int wavesPerBlock = 4;
        const int blocks = (S + wavesPerBlock - 1) / wavesPerBlock;
        router_softmax_top2<<<blocks, wavesPerBlock * 64, 0, stream>>>(
            x, top1, top2, w1, w2, S);
    }

    // 3) per-chunk histograms (packed)
    chunk_hist<<<nchunks, 64, 0, stream>>>(top1, top2, hist);

    // 4) fused scan + ranks + scatter
    rank_scatter<<<nchunks, 64, 0, stream>>>(top1, top2, w1, w2,
                                             hist, out, S, cap, nchunks);
}